// Round 10
// baseline (544.862 us; speedup 1.0000x reference)
//
#include <hip/hip_runtime.h>
#include <math.h>

#define Sn 100
#define Bn 128
#define NWc 430500
#define EWc 431080   // NW + NB

typedef __attribute__((ext_vector_type(8)))  short bhalf8;
typedef __attribute__((ext_vector_type(16))) float fx16;

__device__ __forceinline__ float sp_f(float r){
    return fmaxf(r, 0.f) + log1pf(__expf(-fabsf(r)));   // stable softplus
}
__device__ __forceinline__ ushort bfr(float f){          // fp32 -> bf16 RNE
    union { float f; uint u; } c; c.f = f;
    uint r = (c.u + 0x7FFFu + ((c.u >> 16) & 1u)) >> 16;
    return (ushort)r;
}

// ---------------- K00: softplus(rho) once for ALL params (shared across s) ----------------
__global__ void k00_sp(const float* __restrict__ rho_w, const float* __restrict__ rho_b,
                       float* __restrict__ sp_all){
    int i = blockIdx.x * blockDim.x + threadIdx.x;
    if (i < NWc)      sp_all[i] = sp_f(rho_w[i]);
    else if (i < EWc) sp_all[i] = sp_f(rho_b[i - NWc]);
}

// ---------------- K0b: small params (w1, w2r, w4, ball) ----------------
// w2r layout [s][kk25][oc64][ic32] (round-6 proven; k2's LDS staging depends on it).
__global__ void k0_small(const float* __restrict__ e, const float* __restrict__ mu_w,
                       const float* __restrict__ sp_all, const float* __restrict__ mu_b,
                       float* __restrict__ w1, ushort* __restrict__ w2r,
                       float* __restrict__ w4, float* __restrict__ ball){
    const int per = 31080;  // 500 + 25000 + 5000 + 580
    int idx = blockIdx.x * blockDim.x + threadIdx.x;
    if (idx >= Sn * per) return;
    int s = idx / per, j = idx % per;
    if (j < 500){
        float v = fmaf(sp_all[j], e[(size_t)s*EWc + j], mu_w[j]);
        w1[s*500 + j] = v;
    } else if (j < 25500){
        int g = j;
        float v = fmaf(sp_all[g], e[(size_t)s*EWc + g], mu_w[g]);
        int j2 = j - 500;
        int oc = j2 / 500, rem = j2 % 500;
        int ic = rem / 25, kk = rem % 25;
        w2r[(size_t)s*51200 + (kk*64 + oc)*32 + ic] = bfr(v);
    } else if (j < 30500){
        int g = 425500 + (j - 25500);
        float v = fmaf(sp_all[g], e[(size_t)s*EWc + g], mu_w[g]);
        w4[s*5000 + (j - 25500)] = v;
    } else {
        int k = j - 30500;
        float v = fmaf(sp_all[NWc + k], e[(size_t)s*EWc + NWc + k], mu_b[k]);
        ball[s*580 + k] = v;
    }
}

// ---------------- K1: conv1 + ReLU + 2x2 maxpool ----------------
// h1p bf16 layout: [s][b][pix=y*12+x][ic20]  (channel-last for MFMA k2)
__global__ __launch_bounds__(256, 2) void k1_conv1(const float* __restrict__ x,
        const float* __restrict__ w1, const float* __restrict__ ball,
        ushort* __restrict__ h1p){
    __shared__ __align__(16) float xs[784];
    __shared__ __align__(16) float w1s[500];
    __shared__ float b1s[20];
    __shared__ __align__(16) ushort ots[2880];   // [pix144][ic20] bf16
    int bid = blockIdx.x;
    int s = bid / Bn, b = bid % Bn;
    int tid = threadIdx.x;
    for (int i = tid; i < 784; i += 256) xs[i] = x[b*784 + i];
    for (int i = tid; i < 500; i += 256) w1s[i] = w1[s*500 + i];
    if (tid < 20) b1s[tid] = ball[s*580 + tid];
    __syncthreads();
    if (tid < 240){
        int c = tid / 12, y = tid % 12;   // pooled row y, channel c

        float acc0[24], acc1[24];
        #pragma unroll
        for (int i = 0; i < 24; ++i){ acc0[i] = 0.f; acc1[i] = 0.f; }

        #pragma unroll
        for (int ky = 0; ky < 5; ++ky){
            float rlo[28], rhi[28];
            const float* plo = &xs[(2*y + ky) * 28];
            const float* phi = &xs[(2*y + ky + 1) * 28];
            #pragma unroll
            for (int cc = 0; cc < 28; cc += 4){
                float4 v0 = *(const float4*)(plo + cc);
                rlo[cc] = v0.x; rlo[cc+1] = v0.y; rlo[cc+2] = v0.z; rlo[cc+3] = v0.w;
                float4 v1 = *(const float4*)(phi + cc);
                rhi[cc] = v1.x; rhi[cc+1] = v1.y; rhi[cc+2] = v1.z; rhi[cc+3] = v1.w;
            }
            #pragma unroll
            for (int kx = 0; kx < 5; ++kx){
                float wv = w1s[c*25 + ky*5 + kx];
                #pragma unroll
                for (int cx = 0; cx < 24; ++cx){
                    acc0[cx] = fmaf(rlo[cx + kx], wv, acc0[cx]);
                    acc1[cx] = fmaf(rhi[cx + kx], wv, acc1[cx]);
                }
            }
        }
        float bias = b1s[c];
        #pragma unroll
        for (int px = 0; px < 12; ++px){
            float m = fmaxf(fmaxf(acc0[2*px], acc0[2*px+1]),
                            fmaxf(acc1[2*px], acc1[2*px+1]));
            ots[(y*12 + px)*20 + c] = bfr(fmaxf(m + bias, 0.f));
        }
    }
    __syncthreads();
    const uint* o32 = (const uint*)ots;
    uint* g32 = (uint*)(h1p + (s*Bn + b)*2880);
    for (int j = tid; j < 1440; j += 256) g32[j] = o32[j];
}

// ---------------- K2: conv2 + ReLU + pool via MFMA ----------------
// Round-8 config (measured best ~97 us; k2 plateau -- frozen). LDS-staged B
// (double-buffered, 1 barrier/kk), ic24 stride-48 img, 4 blocks/CU.
// Epilogue/h2p byte-identical: WRITE_SIZE must stay ~20,000 KB (Round-5 lesson).
__global__ __launch_bounds__(256, 4) void k2_direct(const ushort* __restrict__ h1p,
        const ushort* __restrict__ w2r, const float* __restrict__ ball,
        ushort* __restrict__ h2p){
    __shared__ __align__(16) ushort img[4*3456];   // 27,648 B (ic24)
    __shared__ __align__(16) ushort Bls[2][2048];  //  8,192 B (double buffer)
    int bid = blockIdx.x;
    int s = bid >> 5, g = bid & 31;
    int tid = threadIdx.x;
    // stage 4 images: global [im][pix][20] -> LDS [im][pix][24] (ch20-23 zero)
    const uint* g32 = (const uint*)(h1p + (size_t)(s*Bn + g*4)*2880);
    uint* l32 = (uint*)img;
    for (int j = tid; j < 5760; j += 256){            // 4*1440 u32 data
        int im = j / 1440, r = j - im*1440;
        int p = r / 10, u = r - p*10;
        l32[im*1728 + p*12 + u] = g32[j];
    }
    for (int j = tid; j < 1152; j += 256){            // zero pad ch 20..23
        int im = j / 288, r = j - im*288;
        int p = r >> 1, u = 10 + (r & 1);
        l32[im*1728 + p*12 + u] = 0u;
    }

    // B staging: global granule tid (16 B of w2r [kk][oc64][ic32]) -> fragment-
    // order LDS slot. granule: oc = tid>>2, ic-chunk c = tid&3.
    int oc_w = tid >> 2, c_w = tid & 3;
    int P = ((c_w >> 1)*2 + (oc_w >> 5))*64 + (c_w & 1)*32 + (oc_w & 31);
    uint4* bd0 = (uint4*)&Bls[0][P*8];
    uint4* bd1 = (uint4*)&Bls[1][P*8];
    const uint4* bsrc = (const uint4*)(w2r + (size_t)(s*25)*2048) + tid;
    uint4 breg = bsrc[0];                              // kk=0 tile
    *bd0 = breg;                                       // write B tile kk=0

    int wv = tid >> 6, l = tid & 63;
    int l31 = l & 31, q = l >> 5;
    const ushort* imgw = img + wv*3456;
    int pixb0 = ((l31      ) >> 3)*12 + (l31 & 7);    // m-tile 0 pixel base
    int pixb1 = ((l31 + 32 ) >> 3)*12 + (l31 & 7);    // m-tile 1
    int lam = q*32 + l31;                              // fragment slot (lane id)
    fx16 acc00 = (fx16)0.f, acc01 = (fx16)0.f, acc10 = (fx16)0.f, acc11 = (fx16)0.f;
    const bhalf8 zero8 = (bhalf8)(short)0;

    __syncthreads();                                   // img + B0 ready

    #pragma unroll 1
    for (int kk = 0; kk < 25; ++kk){
        int cur = kk & 1;
        if (kk < 24) breg = bsrc[(kk + 1)*256];       // prefetch next 4 KB tile

        int ky = kk / 5, kx = kk - ky*5;
        int poff = ky*12 + kx;
        const ushort* r0 = imgw + (pixb0 + poff)*24;
        const ushort* r1 = imgw + (pixb1 + poff)*24;
        const ushort* Bc = Bls[cur];

        bhalf8 a00 = *(const bhalf8*)(r0 + q*8);      // ic 0-15 (k = q*8..q*8+7)
        bhalf8 a10 = *(const bhalf8*)(r1 + q*8);
        bhalf8 b0  = *(const bhalf8*)&Bc[       lam*8];
        bhalf8 b1  = *(const bhalf8*)&Bc[ 512 + lam*8];
        acc00 = __builtin_amdgcn_mfma_f32_32x32x16_bf16(a00, b0, acc00, 0, 0, 0);
        acc01 = __builtin_amdgcn_mfma_f32_32x32x16_bf16(a00, b1, acc01, 0, 0, 0);
        acc10 = __builtin_amdgcn_mfma_f32_32x32x16_bf16(a10, b0, acc10, 0, 0, 0);
        acc11 = __builtin_amdgcn_mfma_f32_32x32x16_bf16(a10, b1, acc11, 0, 0, 0);

        // tail: ic16-23 live in k=0..7 (q==0 lanes); k=8..15 rows zero (q==1)
        bhalf8 a01 = (q == 0) ? *(const bhalf8*)(r0 + 16) : zero8;
        bhalf8 a11 = (q == 0) ? *(const bhalf8*)(r1 + 16) : zero8;
        bhalf8 b2  = *(const bhalf8*)&Bc[1024 + lam*8];
        bhalf8 b3  = *(const bhalf8*)&Bc[1536 + lam*8];
        acc00 = __builtin_amdgcn_mfma_f32_32x32x16_bf16(a01, b2, acc00, 0, 0, 0);
        acc01 = __builtin_amdgcn_mfma_f32_32x32x16_bf16(a01, b3, acc01, 0, 0, 0);
        acc10 = __builtin_amdgcn_mfma_f32_32x32x16_bf16(a11, b2, acc10, 0, 0, 0);
        acc11 = __builtin_amdgcn_mfma_f32_32x32x16_bf16(a11, b3, acc11, 0, 0, 0);

        if (kk < 24){
            *(cur ? bd0 : bd1) = breg;                 // write tile kk+1 (other buf)
            __syncthreads();                           // orders both buffer hand-offs
        }
    }
    // epilogue: intra-lane 2x2 maxpool, bias+relu, bf16 store in [kt][b][k32] layout
    int b = g*4 + wv;
    ushort* dst = h2p + (size_t)s*102400 + (size_t)b*32;
    #pragma unroll
    for (int nt = 0; nt < 2; ++nt){
        int oc = nt*32 + l31;
        if (oc >= 50) continue;
        float bias = ball[s*580 + 20 + oc];
        #pragma unroll
        for (int mt = 0; mt < 2; ++mt){
            fx16 a;
            if (nt == 0) a = mt ? acc10 : acc00;
            else         a = mt ? acc11 : acc01;
            #pragma unroll
            for (int gp = 0; gp < 2; ++gp){
                float p0 = fmaxf(fmaxf(a[8*gp+0], a[8*gp+1]), fmaxf(a[8*gp+4], a[8*gp+5]));
                float p1 = fmaxf(fmaxf(a[8*gp+2], a[8*gp+3]), fmaxf(a[8*gp+6], a[8*gp+7]));
                p0 = fmaxf(p0 + bias, 0.f);
                p1 = fmaxf(p1 + bias, 0.f);
                int py = mt*2 + gp;
                int i  = oc*16 + py*4 + 2*q;          // flat feature index
                uint pk = (uint)bfr(p0) | ((uint)bfr(p1) << 16);
                *(uint*)(dst + (i >> 5)*4096 + (i & 31)) = pk;
            }
        }
    }
}

// ---------------- K3: aff1 via MFMA, B generated ON THE FLY from e/mu/sp ----------------
// Round-9: k0_w3t deleted. The 160 MB w3 materialize/re-read round-trip was dead
// traffic: k3's B-staging rows map directly onto e's layout (row o0+rr of the
// w3-region = 800 contiguous floats; per-kt chunk = 32 contiguous floats at
// 25500 + (o0+rr)*800 + kt*32; 4 threads/row = 128 B coalesced). B-tile is
// computed bfr(fmaf(sp, e, mu)) in the staging phase; prefetch structure kept.
// mu/sp are shared across s -> L2/L3-resident after first s. bvalid exec-mask
// guards rows o>=500 (e would read OOB on the last s row otherwise).
#define ICS 40   // u16 stride per row in LDS (bank-stagger pad) -- k3 only
__global__ __launch_bounds__(256) void k3_mfma(const ushort* __restrict__ h2p,
        const float* __restrict__ e, const float* __restrict__ mu_w,
        const float* __restrict__ sp_all, const float* __restrict__ ball,
        float* __restrict__ h3){
    __shared__ __align__(16) ushort As[128*ICS];   // 10240 B
    __shared__ __align__(16) ushort Bsh[64*ICS];   //  5120 B
    int bid = blockIdx.x;
    int s = bid >> 3, nblk = bid & 7;
    int o0 = nblk * 64;
    int tid = threadIdx.x;
    int wv = tid >> 6, l = tid & 63, l31 = l & 31, q = l >> 5;
    int wm = wv >> 1, wn = wv & 1;
    fx16 acc0 = (fx16)0.f, acc1 = (fx16)0.f;
    int rr = tid >> 2, rk = (tid & 3)*8;      // staging: row (0..63), k-offset
    const ushort* Abase = h2p + (size_t)s*102400;
    size_t gb = 25500 + (size_t)(o0 + rr)*800 + rk;   // w3-region index, + kt*32
    const float* eb = e + (size_t)s*EWc + gb;
    const float* mb = mu_w   + gb;
    const float* pb = sp_all + gb;
    bool bvalid = (o0 + rr) < 500;

    uint4 ar0, ar1;                           // prefetch kt=0
    float4 ev0, ev1, mv0, mv1, pv0, pv1;
    ar0 = *(const uint4*)(Abase + rr*32 + rk);
    ar1 = *(const uint4*)(Abase + (rr + 64)*32 + rk);
    if (bvalid){
        ev0 = *(const float4*)(eb);     ev1 = *(const float4*)(eb + 4);
        mv0 = *(const float4*)(mb);     mv1 = *(const float4*)(mb + 4);
        pv0 = *(const float4*)(pb);     pv1 = *(const float4*)(pb + 4);
    }

    for (int kt = 0; kt < 25; ++kt){
        __syncthreads();
        *(uint4*)&As[rr*ICS + rk]        = ar0;
        *(uint4*)&As[(rr + 64)*ICS + rk] = ar1;
        uint4 brv = make_uint4(0u,0u,0u,0u);
        if (bvalid){
            brv.x = (uint)bfr(fmaf(pv0.x, ev0.x, mv0.x)) |
                    ((uint)bfr(fmaf(pv0.y, ev0.y, mv0.y)) << 16);
            brv.y = (uint)bfr(fmaf(pv0.z, ev0.z, mv0.z)) |
                    ((uint)bfr(fmaf(pv0.w, ev0.w, mv0.w)) << 16);
            brv.z = (uint)bfr(fmaf(pv1.x, ev1.x, mv1.x)) |
                    ((uint)bfr(fmaf(pv1.y, ev1.y, mv1.y)) << 16);
            brv.w = (uint)bfr(fmaf(pv1.z, ev1.z, mv1.z)) |
                    ((uint)bfr(fmaf(pv1.w, ev1.w, mv1.w)) << 16);
        }
        *(uint4*)&Bsh[rr*ICS + rk] = brv;
        __syncthreads();
        if (kt < 24){                         // prefetch next contiguous chunks
            int ko = (kt + 1)*32;
            ar0 = *(const uint4*)(Abase + (kt+1)*4096 + rr*32 + rk);
            ar1 = *(const uint4*)(Abase + (kt+1)*4096 + (rr + 64)*32 + rk);
            if (bvalid){
                ev0 = *(const float4*)(eb + ko);     ev1 = *(const float4*)(eb + ko + 4);
                mv0 = *(const float4*)(mb + ko);     mv1 = *(const float4*)(mb + ko + 4);
                pv0 = *(const float4*)(pb + ko);     pv1 = *(const float4*)(pb + ko + 4);
            }
        }
        #pragma unroll
        for (int ks = 0; ks < 2; ++ks){
            bhalf8 a0 = *(const bhalf8*)&As[(wm*64      + l31)*ICS + ks*16 + q*8];
            bhalf8 a1 = *(const bhalf8*)&As[(wm*64 + 32 + l31)*ICS + ks*16 + q*8];
            bhalf8 bb = *(const bhalf8*)&Bsh[(wn*32 + l31)*ICS + ks*16 + q*8];
            acc0 = __builtin_amdgcn_mfma_f32_32x32x16_bf16(a0, bb, acc0, 0, 0, 0);
            acc1 = __builtin_amdgcn_mfma_f32_32x32x16_bf16(a1, bb, acc1, 0, 0, 0);
        }
    }
    int o = o0 + wn*32 + l31;
    if (o < 500){
        float bias = ball[s*580 + 70 + o];
        #pragma unroll
        for (int mt = 0; mt < 2; ++mt){
            fx16 a = mt ? acc1 : acc0;
            #pragma unroll
            for (int reg = 0; reg < 16; ++reg){
                int row = (reg & 3) + 8*(reg >> 2) + 4*q;
                int b = wm*64 + mt*32 + row;
                h3[(size_t)(s*Bn + b)*500 + o] = fmaxf(a[reg] + bias, 0.f);
            }
        }
    }
}

// ---------------- K4a: aff2 + log_softmax per (s,b) ----------------
__global__ __launch_bounds__(256) void k4a(const float* __restrict__ h3,
        const float* __restrict__ w4, const float* __restrict__ ball,
        float* __restrict__ lsw){
    int wv = threadIdx.x >> 6, lane = threadIdx.x & 63;
    int p = blockIdx.x*4 + wv;
    int s = p / Bn;
    const float* hp = &h3[(size_t)p*500];
    const float* wp = &w4[(size_t)s*5000];
    float part[10];
    #pragma unroll
    for (int o = 0; o < 10; ++o) part[o] = 0.f;
    for (int i = lane; i < 500; i += 64){
        float hv = hp[i];
        #pragma unroll
        for (int o = 0; o < 10; ++o)
            part[o] = fmaf(hv, wp[o*500 + i], part[o]);
    }
    #pragma unroll
    for (int o = 0; o < 10; ++o){
        #pragma unroll
        for (int d = 1; d < 64; d <<= 1)
            part[o] += __shfl_xor(part[o], d);
    }
    float v[10]; float m = -INFINITY;
    #pragma unroll
    for (int o = 0; o < 10; ++o){
        v[o] = part[o] + ball[s*580 + 570 + o];
        m = fmaxf(m, v[o]);
    }
    float sum = 0.f;
    #pragma unroll
    for (int o = 0; o < 10; ++o) sum += __expf(v[o] - m);
    float lse = m + __logf(sum);
    if (lane == 0){
        #pragma unroll
        for (int o = 0; o < 10; ++o) lsw[p*10 + o] = v[o] - lse;
    }
}

// ---------------- K4b: mean over samples ----------------
__global__ void k4b(const float* __restrict__ lsw, float* __restrict__ outp){
    int j = blockIdx.x * blockDim.x + threadIdx.x;
    if (j >= Bn*10) return;
    int b = j / 10, o = j % 10;
    float acc = 0.f;
    for (int s2 = 0; s2 < Sn; ++s2) acc += lsw[(s2*Bn + b)*10 + o];
    outp[j] = acc * (1.f / (float)Sn);
}

extern "C" void kernel_launch(void* const* d_in, const int* in_sizes, int n_in,
                              void* d_out, int out_size, void* d_ws, size_t ws_size,
                              hipStream_t stream){
    const float* x     = (const float*)d_in[0];
    const float* e     = (const float*)d_in[1];
    const float* mu_w  = (const float*)d_in[2];
    const float* rho_w = (const float*)d_in[3];
    const float* mu_b  = (const float*)d_in[4];
    const float* rho_b = (const float*)d_in[5];
    float* ws   = (float*)d_ws;
    float* w1     = ws;                       //     50,000 f
    float* w4     = w1 + 50000;               //    500,000 f
    float* ball   = w4 + 500000;              //     58,000 f
    float* h3     = ball + 58000;             //  6,400,000 f
    float* lsw    = h3 + 6400000;             //    128,000 f
    float* sp_all = lsw + 128000;             //    431,080 f
    ushort* h1p = (ushort*)(sp_all + 431080); // 36,864,000 u16
    ushort* h2p = h1p + 36864000;             // 10,240,000 u16
    ushort* w2r = h2p + 10240000;             //  5,120,000 u16
    float* outp = (float*)d_out;

    hipMemsetAsync(w2r, 0, (size_t)Sn*51200*2, stream);
    k00_sp   <<<(EWc + 255)/256, 256, 0, stream>>>(rho_w, rho_b, sp_all);
    k0_small <<<(Sn*31080 + 255)/256, 256, 0, stream>>>(e, mu_w, sp_all, mu_b, w1, w2r, w4, ball);
    k1_conv1 <<<Sn*Bn, 256, 0, stream>>>(x, w1, ball, h1p);
    k2_direct<<<Sn*32, 256, 0, stream>>>(h1p, w2r, ball, h2p);
    k3_mfma  <<<Sn*8, 256, 0, stream>>>(h2p, e, mu_w, sp_all, ball, h3);
    k4a      <<<3200, 256, 0, stream>>>(h3, w4, ball, lsw);
    k4b      <<<(Bn*10 + 255)/256, 256, 0, stream>>>(lsw, outp);
}

// Round 11
// 517.412 us; speedup vs baseline: 1.0531x; 1.0531x over previous
//
#include <hip/hip_runtime.h>
#include <math.h>

#define Sn 100
#define Bn 128
#define NWc 430500
#define EWc 431080   // NW + NB

typedef __attribute__((ext_vector_type(8)))  short bhalf8;
typedef __attribute__((ext_vector_type(16))) float fx16;

__device__ __forceinline__ float sp_f(float r){
    return fmaxf(r, 0.f) + log1pf(__expf(-fabsf(r)));   // stable softplus
}
__device__ __forceinline__ ushort bfr(float f){          // fp32 -> bf16 RNE
    union { float f; uint u; } c; c.f = f;
    uint r = (c.u + 0x7FFFu + ((c.u >> 16) & 1u)) >> 16;
    return (ushort)r;
}

// ---------------- K00: softplus(rho) once for ALL params (shared across s) ----------------
__global__ void k00_sp(const float* __restrict__ rho_w, const float* __restrict__ rho_b,
                       float* __restrict__ sp_all){
    int i = blockIdx.x * blockDim.x + threadIdx.x;
    if (i < NWc)      sp_all[i] = sp_f(rho_w[i]);
    else if (i < EWc) sp_all[i] = sp_f(rho_b[i - NWc]);
}

// ---------------- K0a: w3 bf16 [s][kt25][o500][k32] via LDS transpose ----------------
// RESTORED (round-9 lesson: this materialize pass converts strided->linear
// access for k3's B; fusing it into k3 made k3 latency-bound, 145 us).
// 2 samples per block: mu_w/sp_all loaded once per s-pair.
__global__ __launch_bounds__(256) void k0_w3t(const float* __restrict__ e,
        const float* __restrict__ mu_w, const float* __restrict__ sp_all,
        ushort* __restrict__ w3){
    __shared__ __align__(16) ushort ls[2][20*808];   // 64,640 B
    int oc = blockIdx.x;      // 0..24  (o-chunk of 20 rows)
    int sp = blockIdx.y;      // 0..49  (s-pair)
    int s0 = sp * 2;
    int o0 = oc * 20;
    int tid = threadIdx.x;
    const float* e0 = e + (size_t)s0*EWc + 25500 + (size_t)o0*800;
    const float* e1 = e0 + EWc;
    const float* mb = mu_w   + 25500 + (size_t)o0*800;
    const float* pb = sp_all + 25500 + (size_t)o0*800;
    #pragma unroll 2
    for (int j = tid; j < 4000; j += 256){        // 4000 float4 = 16000 floats
        int o = j / 200, k4 = j - o*200;
        float4 mv = *(const float4*)(mb + j*4);
        float4 sv = *(const float4*)(pb + j*4);
        float4 ev0 = *(const float4*)(e0 + j*4);
        float4 ev1 = *(const float4*)(e1 + j*4);
        ushort4 t0, t1;
        t0.x = bfr(fmaf(sv.x, ev0.x, mv.x));
        t0.y = bfr(fmaf(sv.y, ev0.y, mv.y));
        t0.z = bfr(fmaf(sv.z, ev0.z, mv.z));
        t0.w = bfr(fmaf(sv.w, ev0.w, mv.w));
        t1.x = bfr(fmaf(sv.x, ev1.x, mv.x));
        t1.y = bfr(fmaf(sv.y, ev1.y, mv.y));
        t1.z = bfr(fmaf(sv.z, ev1.z, mv.z));
        t1.w = bfr(fmaf(sv.w, ev1.w, mv.w));
        *(ushort4*)&ls[0][o*808 + k4*4] = t0;
        *(ushort4*)&ls[1][o*808 + k4*4] = t1;
    }
    __syncthreads();
    if (tid < 200){
        int kt = tid >> 3, l8 = tid & 7;          // 8 lanes per kt stripe
        #pragma unroll
        for (int ss = 0; ss < 2; ++ss){
            ushort* wb = w3 + (size_t)(s0 + ss)*400000 + kt*16000 + o0*32;
            #pragma unroll
            for (int it = 0; it < 10; ++it){
                int idx = it*8 + l8;              // 0..79 uint4 per stripe
                int o = idx >> 2, kp = (idx & 3)*8;
                uint4 v = *(const uint4*)&ls[ss][o*808 + kt*32 + kp];
                *(uint4*)(wb + idx*8) = v;        // 8 lanes -> 128 B contiguous
            }
        }
    }
}

// ---------------- K0b: small params (w1, w2r, w4, ball) ----------------
// w2r layout [s][kk25][oc64][ic32] (round-6 proven; k2's LDS staging depends on it).
__global__ void k0_small(const float* __restrict__ e, const float* __restrict__ mu_w,
                       const float* __restrict__ sp_all, const float* __restrict__ mu_b,
                       float* __restrict__ w1, ushort* __restrict__ w2r,
                       float* __restrict__ w4, float* __restrict__ ball){
    const int per = 31080;  // 500 + 25000 + 5000 + 580
    int idx = blockIdx.x * blockDim.x + threadIdx.x;
    if (idx >= Sn * per) return;
    int s = idx / per, j = idx % per;
    if (j < 500){
        float v = fmaf(sp_all[j], e[(size_t)s*EWc + j], mu_w[j]);
        w1[s*500 + j] = v;
    } else if (j < 25500){
        int g = j;
        float v = fmaf(sp_all[g], e[(size_t)s*EWc + g], mu_w[g]);
        int j2 = j - 500;
        int oc = j2 / 500, rem = j2 % 500;
        int ic = rem / 25, kk = rem % 25;
        w2r[(size_t)s*51200 + (kk*64 + oc)*32 + ic] = bfr(v);
    } else if (j < 30500){
        int g = 425500 + (j - 25500);
        float v = fmaf(sp_all[g], e[(size_t)s*EWc + g], mu_w[g]);
        w4[s*5000 + (j - 25500)] = v;
    } else {
        int k = j - 30500;
        float v = fmaf(sp_all[NWc + k], e[(size_t)s*EWc + NWc + k], mu_b[k]);
        ball[s*580 + k] = v;
    }
}

// ---------------- K1: conv1 + ReLU + 2x2 maxpool via MFMA ----------------
// Round-10 rewrite: conv1's 7.4 G vector-FLOPs (fp32 VALU, ~85 us) moved to
// matrix cores. Per image: im2col A[576 pix][K=25 pad 32] bf16 in LDS
// (XOR-swizzled, k2's proven pattern), B = w1[oc20 pad 32][K] bf16 (2 KB LDS,
// kept in regs), 18 M-tiles x 2 K-halves = 36 MFMAs. pix ordered POOL-QUAD-
// MAJOR: p' = (ypool*12+xpool)*4 + (y&1)*2 + (x&1), so the 32x32 C layout
// (row=(reg&3)+8*rg+4*q) puts each 2x2 pool quad in 4 consecutive regs of one
// lane -> intra-lane pooling (k2's epilogue pattern). Accum fp32; only A/B
// inputs are bf16-rounded (h1 was already stored bf16). h1p layout unchanged.
__global__ __launch_bounds__(256, 3) void k1_conv1(const float* __restrict__ x,
        const float* __restrict__ w1, const float* __restrict__ ball,
        ushort* __restrict__ h1p){
    __shared__ __align__(16) float xs[784];          //  3,136 B
    __shared__ __align__(16) ushort As[576*32];      // 36,864 B (swizzled)
    __shared__ __align__(16) ushort w1b[1024];       //  2,048 B [oc32][k32]
    __shared__ __align__(16) ushort ots[2880];       //  2,880 B [pix144][ic20]
    int bid = blockIdx.x;
    int s = bid / Bn, b = bid % Bn;
    int tid = threadIdx.x;
    for (int i = tid; i < 784; i += 256) xs[i] = x[b*784 + i];
    {   // B tile: w1b[oc][k] = bf16(w1[s*500 + oc*25 + k]), zero pad oc>=20||k>=25
        int i0 = tid*4;
        int oc = i0 >> 5, k0 = i0 & 31;
        ushort4 v; ushort* vp = (ushort*)&v;
        #pragma unroll
        for (int jj = 0; jj < 4; ++jj){
            int k = k0 + jj;
            vp[jj] = (oc < 20 && k < 25) ? bfr(w1[s*500 + oc*25 + k]) : (ushort)0;
        }
        *(ushort4*)&w1b[i0] = v;
    }
    __syncthreads();                                  // xs + w1b ready

    // Phase 1: im2col staging, rows p' = tid, tid+256, tid+512
    for (int p = tid; p < 576; p += 256){
        int quad = p >> 2, sub = p & 3;
        int yp = quad / 12, xp = quad - yp*12;
        int y = 2*yp + (sub >> 1), xx = 2*xp + (sub & 1);
        ushort vals[25];
        #pragma unroll
        for (int ky = 0; ky < 5; ++ky){
            const float* rowp = &xs[(y + ky)*28 + xx];
            #pragma unroll
            for (int kx = 0; kx < 5; ++kx)
                vals[ky*5 + kx] = bfr(rowp[kx]);
        }
        uint pk[16];
        #pragma unroll
        for (int j = 0; j < 12; ++j)
            pk[j] = (uint)vals[2*j] | ((uint)vals[2*j+1] << 16);
        pk[12] = (uint)vals[24];                      // k24 | 0
        pk[13] = 0u; pk[14] = 0u; pk[15] = 0u;
        uint* dst = (uint*)As;
        int base = p*16, sw = (p & 7) << 2;           // u32 index + XOR (bits 2-4)
        #pragma unroll
        for (int c = 0; c < 4; ++c)
            *(uint4*)&dst[(base + c*4) ^ sw] =
                make_uint4(pk[c*4], pk[c*4+1], pk[c*4+2], pk[c*4+3]);
    }

    int wv = tid >> 6, l = tid & 63;
    int l31 = l & 31, q = l >> 5;
    // B fragments (constant across tiles)
    __syncthreads();                                  // As ready
    bhalf8 b0 = *(const bhalf8*)&w1b[l31*32 +      q*8];   // k 0..15
    bhalf8 b1 = *(const bhalf8*)&w1b[l31*32 + 16 + q*8];   // k 16..31
    float bias = (l31 < 20) ? ball[s*580 + l31] : 0.f;

    // Phase 2: MFMA + pooled epilogue; wave wv owns tiles wv, wv+4, ...
    for (int t = wv; t < 18; t += 4){
        int row0 = t*32 + l31;
        int swz = (row0 & 7) << 3;                    // u16 XOR (bits 3-5)
        bhalf8 a0 = *(const bhalf8*)&As[(row0*32 +      q*8) ^ swz];
        bhalf8 a1 = *(const bhalf8*)&As[(row0*32 + 16 + q*8) ^ swz];
        fx16 acc = (fx16)0.f;
        acc = __builtin_amdgcn_mfma_f32_32x32x16_bf16(a0, b0, acc, 0, 0, 0);
        acc = __builtin_amdgcn_mfma_f32_32x32x16_bf16(a1, b1, acc, 0, 0, 0);
        if (l31 < 20){
            #pragma unroll
            for (int rg = 0; rg < 4; ++rg){
                float m = fmaxf(fmaxf(acc[4*rg], acc[4*rg+1]),
                                fmaxf(acc[4*rg+2], acc[4*rg+3]));
                int pout = t*8 + 2*rg + q;            // pool-quad = pix144 index
                ots[pout*20 + l31] = bfr(fmaxf(m + bias, 0.f));
            }
        }
    }
    __syncthreads();
    const uint* o32 = (const uint*)ots;
    uint* g32 = (uint*)(h1p + (s*Bn + b)*2880);
    for (int j = tid; j < 1440; j += 256) g32[j] = o32[j];
}

// ---------------- K2: conv2 + ReLU + pool via MFMA ----------------
// Round-8 config (measured best ~97 us; frozen). LDS-staged B (double-buffered,
// 1 barrier/kk), ic24 stride-48 img, 4 blocks/CU.
// Epilogue/h2p byte-identical: WRITE_SIZE must stay ~20,000 KB (Round-5 lesson).
__global__ __launch_bounds__(256, 4) void k2_direct(const ushort* __restrict__ h1p,
        const ushort* __restrict__ w2r, const float* __restrict__ ball,
        ushort* __restrict__ h2p){
    __shared__ __align__(16) ushort img[4*3456];   // 27,648 B (ic24)
    __shared__ __align__(16) ushort Bls[2][2048];  //  8,192 B (double buffer)
    int bid = blockIdx.x;
    int s = bid >> 5, g = bid & 31;
    int tid = threadIdx.x;
    // stage 4 images: global [im][pix][20] -> LDS [im][pix][24] (ch20-23 zero)
    const uint* g32 = (const uint*)(h1p + (size_t)(s*Bn + g*4)*2880);
    uint* l32 = (uint*)img;
    for (int j = tid; j < 5760; j += 256){            // 4*1440 u32 data
        int im = j / 1440, r = j - im*1440;
        int p = r / 10, u = r - p*10;
        l32[im*1728 + p*12 + u] = g32[j];
    }
    for (int j = tid; j < 1152; j += 256){            // zero pad ch 20..23
        int im = j / 288, r = j - im*288;
        int p = r >> 1, u = 10 + (r & 1);
        l32[im*1728 + p*12 + u] = 0u;
    }

    // B staging: global granule tid (16 B of w2r [kk][oc64][ic32]) -> fragment-
    // order LDS slot. granule: oc = tid>>2, ic-chunk c = tid&3.
    int oc_w = tid >> 2, c_w = tid & 3;
    int P = ((c_w >> 1)*2 + (oc_w >> 5))*64 + (c_w & 1)*32 + (oc_w & 31);
    uint4* bd0 = (uint4*)&Bls[0][P*8];
    uint4* bd1 = (uint4*)&Bls[1][P*8];
    const uint4* bsrc = (const uint4*)(w2r + (size_t)(s*25)*2048) + tid;
    uint4 breg = bsrc[0];                              // kk=0 tile
    *bd0 = breg;                                       // write B tile kk=0

    int wv = tid >> 6, l = tid & 63;
    int l31 = l & 31, q = l >> 5;
    const ushort* imgw = img + wv*3456;
    int pixb0 = ((l31      ) >> 3)*12 + (l31 & 7);    // m-tile 0 pixel base
    int pixb1 = ((l31 + 32 ) >> 3)*12 + (l31 & 7);    // m-tile 1
    int lam = q*32 + l31;                              // fragment slot (lane id)
    fx16 acc00 = (fx16)0.f, acc01 = (fx16)0.f, acc10 = (fx16)0.f, acc11 = (fx16)0.f;
    const bhalf8 zero8 = (bhalf8)(short)0;

    __syncthreads();                                   // img + B0 ready

    #pragma unroll 1
    for (int kk = 0; kk < 25; ++kk){
        int cur = kk & 1;
        if (kk < 24) breg = bsrc[(kk + 1)*256];       // prefetch next 4 KB tile

        int ky = kk / 5, kx = kk - ky*5;
        int poff = ky*12 + kx;
        const ushort* r0 = imgw + (pixb0 + poff)*24;
        const ushort* r1 = imgw + (pixb1 + poff)*24;
        const ushort* Bc = Bls[cur];

        bhalf8 a00 = *(const bhalf8*)(r0 + q*8);      // ic 0-15 (k = q*8..q*8+7)
        bhalf8 a10 = *(const bhalf8*)(r1 + q*8);
        bhalf8 b0  = *(const bhalf8*)&Bc[       lam*8];
        bhalf8 b1  = *(const bhalf8*)&Bc[ 512 + lam*8];
        acc00 = __builtin_amdgcn_mfma_f32_32x32x16_bf16(a00, b0, acc00, 0, 0, 0);
        acc01 = __builtin_amdgcn_mfma_f32_32x32x16_bf16(a00, b1, acc01, 0, 0, 0);
        acc10 = __builtin_amdgcn_mfma_f32_32x32x16_bf16(a10, b0, acc10, 0, 0, 0);
        acc11 = __builtin_amdgcn_mfma_f32_32x32x16_bf16(a10, b1, acc11, 0, 0, 0);

        // tail: ic16-23 live in k=0..7 (q==0 lanes); k=8..15 rows zero (q==1)
        bhalf8 a01 = (q == 0) ? *(const bhalf8*)(r0 + 16) : zero8;
        bhalf8 a11 = (q == 0) ? *(const bhalf8*)(r1 + 16) : zero8;
        bhalf8 b2  = *(const bhalf8*)&Bc[1024 + lam*8];
        bhalf8 b3  = *(const bhalf8*)&Bc[1536 + lam*8];
        acc00 = __builtin_amdgcn_mfma_f32_32x32x16_bf16(a01, b2, acc00, 0, 0, 0);
        acc01 = __builtin_amdgcn_mfma_f32_32x32x16_bf16(a01, b3, acc01, 0, 0, 0);
        acc10 = __builtin_amdgcn_mfma_f32_32x32x16_bf16(a11, b2, acc10, 0, 0, 0);
        acc11 = __builtin_amdgcn_mfma_f32_32x32x16_bf16(a11, b3, acc11, 0, 0, 0);

        if (kk < 24){
            *(cur ? bd0 : bd1) = breg;                 // write tile kk+1 (other buf)
            __syncthreads();                           // orders both buffer hand-offs
        }
    }
    // epilogue: intra-lane 2x2 maxpool, bias+relu, bf16 store in [kt][b][k32] layout
    int b = g*4 + wv;
    ushort* dst = h2p + (size_t)s*102400 + (size_t)b*32;
    #pragma unroll
    for (int nt = 0; nt < 2; ++nt){
        int oc = nt*32 + l31;
        if (oc >= 50) continue;
        float bias = ball[s*580 + 20 + oc];
        #pragma unroll
        for (int mt = 0; mt < 2; ++mt){
            fx16 a;
            if (nt == 0) a = mt ? acc10 : acc00;
            else         a = mt ? acc11 : acc01;
            #pragma unroll
            for (int gp = 0; gp < 2; ++gp){
                float p0 = fmaxf(fmaxf(a[8*gp+0], a[8*gp+1]), fmaxf(a[8*gp+4], a[8*gp+5]));
                float p1 = fmaxf(fmaxf(a[8*gp+2], a[8*gp+3]), fmaxf(a[8*gp+6], a[8*gp+7]));
                p0 = fmaxf(p0 + bias, 0.f);
                p1 = fmaxf(p1 + bias, 0.f);
                int py = mt*2 + gp;
                int i  = oc*16 + py*4 + 2*q;          // flat feature index
                uint pk = (uint)bfr(p0) | ((uint)bfr(p1) << 16);
                *(uint*)(dst + (i >> 5)*4096 + (i & 31)) = pk;
            }
        }
    }
}

// ---------------- K3: aff1 via MFMA (per s: 128 x 512pad x 800) -- RESTORED round-8 ------
// A = h2p [s][kt][b128][k32], B = w3 [s][kt][o500][k32]; register-prefetched LDS staging.
// h3 fp32 [s][b][o500]
#define ICS 40   // u16 stride per row in LDS (bank-stagger pad) -- k3 only
__global__ __launch_bounds__(256) void k3_mfma(const ushort* __restrict__ h2p,
        const ushort* __restrict__ w3, const float* __restrict__ ball,
        float* __restrict__ h3){
    __shared__ __align__(16) ushort As[128*ICS];   // 10240 B
    __shared__ __align__(16) ushort Bsh[64*ICS];   //  5120 B
    int bid = blockIdx.x;
    int s = bid >> 3, nblk = bid & 7;
    int o0 = nblk * 64;
    int tid = threadIdx.x;
    int wv = tid >> 6, l = tid & 63, l31 = l & 31, q = l >> 5;
    int wm = wv >> 1, wn = wv & 1;
    fx16 acc0 = (fx16)0.f, acc1 = (fx16)0.f;
    int rr = tid >> 2, rk = (tid & 3)*8;      // staging: row (0..63), k-offset
    const ushort* Abase = h2p + (size_t)s*102400;
    const ushort* Bbase = w3  + (size_t)s*400000 + (size_t)o0*32;
    bool bvalid = (o0 + rr) < 500;
    const uint4 z4 = make_uint4(0u,0u,0u,0u);

    uint4 ar0, ar1, br;                       // prefetch kt=0
    ar0 = *(const uint4*)(Abase + rr*32 + rk);
    ar1 = *(const uint4*)(Abase + (rr + 64)*32 + rk);
    br  = bvalid ? *(const uint4*)(Bbase + rr*32 + rk) : z4;

    for (int kt = 0; kt < 25; ++kt){
        __syncthreads();
        *(uint4*)&As[rr*ICS + rk]        = ar0;
        *(uint4*)&As[(rr + 64)*ICS + rk] = ar1;
        *(uint4*)&Bsh[rr*ICS + rk]       = br;
        __syncthreads();
        if (kt < 24){                         // prefetch next contiguous chunks
            ar0 = *(const uint4*)(Abase + (kt+1)*4096 + rr*32 + rk);
            ar1 = *(const uint4*)(Abase + (kt+1)*4096 + (rr + 64)*32 + rk);
            br  = bvalid ? *(const uint4*)(Bbase + (kt+1)*16000 + rr*32 + rk) : z4;
        }
        #pragma unroll
        for (int ks = 0; ks < 2; ++ks){
            bhalf8 a0 = *(const bhalf8*)&As[(wm*64      + l31)*ICS + ks*16 + q*8];
            bhalf8 a1 = *(const bhalf8*)&As[(wm*64 + 32 + l31)*ICS + ks*16 + q*8];
            bhalf8 bb = *(const bhalf8*)&Bsh[(wn*32 + l31)*ICS + ks*16 + q*8];
            acc0 = __builtin_amdgcn_mfma_f32_32x32x16_bf16(a0, bb, acc0, 0, 0, 0);
            acc1 = __builtin_amdgcn_mfma_f32_32x32x16_bf16(a1, bb, acc1, 0, 0, 0);
        }
    }
    int o = o0 + wn*32 + l31;
    if (o < 500){
        float bias = ball[s*580 + 70 + o];
        #pragma unroll
        for (int mt = 0; mt < 2; ++mt){
            fx16 a = mt ? acc1 : acc0;
            #pragma unroll
            for (int reg = 0; reg < 16; ++reg){
                int row = (reg & 3) + 8*(reg >> 2) + 4*q;
                int b = wm*64 + mt*32 + row;
                h3[(size_t)(s*Bn + b)*500 + o] = fmaxf(a[reg] + bias, 0.f);
            }
        }
    }
}

// ---------------- K4a: aff2 + log_softmax per (s,b) ----------------
__global__ __launch_bounds__(256) void k4a(const float* __restrict__ h3,
        const float* __restrict__ w4, const float* __restrict__ ball,
        float* __restrict__ lsw){
    int wv = threadIdx.x >> 6, lane = threadIdx.x & 63;
    int p = blockIdx.x*4 + wv;
    int s = p / Bn;
    const float* hp = &h3[(size_t)p*500];
    const float* wp = &w4[(size_t)s*5000];
    float part[10];
    #pragma unroll
    for (int o = 0; o < 10; ++o) part[o] = 0.f;
    for (int i = lane; i < 500; i += 64){
        float hv = hp[i];
        #pragma unroll
        for (int o = 0; o < 10; ++o)
            part[o] = fmaf(hv, wp[o*500 + i], part[o]);
    }
    #pragma unroll
    for (int o = 0; o < 10; ++o){
        #pragma unroll
        for (int d = 1; d < 64; d <<= 1)
            part[o] += __shfl_xor(part[o], d);
    }
    float v[10]; float m = -INFINITY;
    #pragma unroll
    for (int o = 0; o < 10; ++o){
        v[o] = part[o] + ball[s*580 + 570 + o];
        m = fmaxf(m, v[o]);
    }
    float sum = 0.f;
    #pragma unroll
    for (int o = 0; o < 10; ++o) sum += __expf(v[o] - m);
    float lse = m + __logf(sum);
    if (lane == 0){
        #pragma unroll
        for (int o = 0; o < 10; ++o) lsw[p*10 + o] = v[o] - lse;
    }
}

// ---------------- K4b: mean over samples ----------------
__global__ void k4b(const float* __restrict__ lsw, float* __restrict__ outp){
    int j = blockIdx.x * blockDim.x + threadIdx.x;
    if (j >= Bn*10) return;
    int b = j / 10, o = j % 10;
    float acc = 0.f;
    for (int s2 = 0; s2 < Sn; ++s2) acc += lsw[(s2*Bn + b)*10 + o];
    outp[j] = acc * (1.f / (float)Sn);
}

extern "C" void kernel_launch(void* const* d_in, const int* in_sizes, int n_in,
                              void* d_out, int out_size, void* d_ws, size_t ws_size,
                              hipStream_t stream){
    const float* x     = (const float*)d_in[0];
    const float* e     = (const float*)d_in[1];
    const float* mu_w  = (const float*)d_in[2];
    const float* rho_w = (const float*)d_in[3];
    const float* mu_b  = (const float*)d_in[4];
    const float* rho_b = (const float*)d_in[5];
    float* ws   = (float*)d_ws;
    float* w1     = ws;                       //     50,000 f
    float* w4     = w1 + 50000;               //    500,000 f
    float* ball   = w4 + 500000;              //     58,000 f
    float* h3     = ball + 58000;             //  6,400,000 f
    float* lsw    = h3 + 6400000;             //    128,000 f
    float* sp_all = lsw + 128000;             //    431,080 f
    ushort* h1p = (ushort*)(sp_all + 431080); // 36,864,000 u16
    ushort* h2p = h1p + 36864000;             // 10,240,000 u16
    ushort* w2r = h2p + 10240000;             //  5,120,000 u16
    ushort* w3  = w2r + 5120000;              // 40,000,000 u16 (80 MB)
    float* outp = (float*)d_out;

    hipMemsetAsync(w2r, 0, (size_t)Sn*51200*2, stream);
    k00_sp   <<<(EWc + 255)/256, 256, 0, stream>>>(rho_w, rho_b, sp_all);
    k0_w3t   <<<dim3(25, 50), 256, 0, stream>>>(e, mu_w, sp_all, w3);
    k0_small <<<(Sn*31080 + 255)/256, 256, 0, stream>>>(e, mu_w, sp_all, mu_b, w1, w2r, w4, ball);
    k1_conv1 <<<Sn*Bn, 256, 0, stream>>>(x, w1, ball, h1p);
    k2_direct<<<Sn*32, 256, 0, stream>>>(h1p, w2r, ball, h2p);
    k3_mfma  <<<Sn*8, 256, 0, stream>>>(h2p, w3, ball, h3);
    k4a      <<<3200, 256, 0, stream>>>(h3, w4, ball, lsw);
    k4b      <<<(Bn*10 + 255)/256, 256, 0, stream>>>(lsw, outp);
}